// Round 1
// baseline (1312.305 us; speedup 1.0000x reference)
//
#include <hip/hip_runtime.h>
#include <hip/hip_bf16.h>
#include <cstdint>
#include <cstddef>

typedef __bf16 bf16_t;
typedef __bf16 bf16x8 __attribute__((ext_vector_type(8)));
typedef float  f32x4  __attribute__((ext_vector_type(4)));

#define TOKENS 16384
#define HIDDEN 2048
#define FFN    8192

// ---------------------------------------------------------------------------
// async global -> LDS, 16B per lane. LDS dest must be the WAVE-UNIFORM base;
// hardware writes base + lane*16. Global src is per-lane.
// ---------------------------------------------------------------------------
__device__ __forceinline__ void gload_lds16(const bf16_t* g, bf16_t* l) {
    __builtin_amdgcn_global_load_lds((const __attribute__((address_space(1))) void*)g,
                                     (__attribute__((address_space(3))) void*)l,
                                     16, 0, 0);
}

// ---------------------------------------------------------------------------
// f32 -> bf16 elementwise convert, 8 elems/thread (float4 x2 in, bf16x8 out)
// ---------------------------------------------------------------------------
__global__ void cvt_f32_to_bf16(const float* __restrict__ in, bf16_t* __restrict__ out, int n8) {
    int i = blockIdx.x * blockDim.x + threadIdx.x;
    if (i >= n8) return;
    size_t base = (size_t)i * 8;
    f32x4 v0 = *(const f32x4*)&in[base];
    f32x4 v1 = *(const f32x4*)&in[base + 4];
    bf16x8 o;
    o[0] = (bf16_t)v0[0]; o[1] = (bf16_t)v0[1]; o[2] = (bf16_t)v0[2]; o[3] = (bf16_t)v0[3];
    o[4] = (bf16_t)v1[0]; o[5] = (bf16_t)v1[1]; o[6] = (bf16_t)v1[2]; o[7] = (bf16_t)v1[3];
    *(bf16x8*)&out[base] = o;
}

// ---------------------------------------------------------------------------
// Transpose + convert: src (R x C, f32, row-major) -> dst (C x R, bf16, row-major)
// 64x64 tiles, 256 threads. LDS row stride 66 elems (33 words) -> conflict-free
// column reads.
// ---------------------------------------------------------------------------
__global__ void transpose_cvt(const float* __restrict__ src, bf16_t* __restrict__ dst,
                              int R, int C) {
    __shared__ bf16_t tile[64][66];
    const int tcols = C >> 6;
    const int bx = blockIdx.x % tcols;   // col tile of src
    const int by = blockIdx.x / tcols;   // row tile of src
    const int c0 = bx << 6, r0 = by << 6;
    const int t = threadIdx.x;
#pragma unroll
    for (int i = 0; i < 16; ++i) {
        int idx = i * 256 + t;
        int rr = idx >> 6, cc = idx & 63;
        tile[rr][cc] = (bf16_t)src[(size_t)(r0 + rr) * C + (c0 + cc)];
    }
    __syncthreads();
#pragma unroll
    for (int i = 0; i < 16; ++i) {
        int idx = i * 256 + t;
        int cc = idx >> 6, rr = idx & 63;
        dst[(size_t)(c0 + cc) * R + (r0 + rr)] = tile[rr][cc];
    }
}

// ---------------------------------------------------------------------------
// GEMM: C(MxN) = A(MxK) @ BT(NxK)^T  [+ bias, optional exact-erf GELU]
// m97 structure: 128x128 tile, BK=64, 4 waves (2x2), each wave 64x64 out via
// 4x4 fragments of mfma_f32_16x16x32_bf16. global_load_lds width-16 staging,
// linear LDS, 2 barriers per K-step.
// ---------------------------------------------------------------------------
template<bool GELU_EPI, int M, int N, int K>
__global__ __launch_bounds__(256, 2)
void gemm_bt(const bf16_t* __restrict__ A,
             const bf16_t* __restrict__ BT,
             const float* __restrict__ bias,
             void* __restrict__ out)
{
    constexpr int BM = 128, BN = 128, BK = 64;
    __shared__ bf16_t As[BM * BK];   // [128][64] row-major (row=M, col=k)
    __shared__ bf16_t Bs[BN * BK];   // [128][64] row-major (row=N, col=k)

    const int t    = threadIdx.x;
    const int wave = t >> 6;
    const int lane = t & 63;
    const int bn = blockIdx.x % (N / BN);
    const int bm = blockIdx.x / (N / BN);

    const int wr = wave >> 1;        // wave row 0..1 (64-row slab)
    const int wc = wave & 1;         // wave col 0..1 (64-col slab)
    const int fr = lane & 15;        // fragment row/col index
    const int fq = lane >> 4;        // k-quad (0..3)

    f32x4 acc[4][4] = {};

    // staging geometry: chunk = p*4 + wave, each chunk = 512 elems (8 rows x 64)
    const int srow = wave * 8 + (lane >> 3);   // row for pass 0
    const int scol = (lane & 7) * 8;           // k-offset within tile
    const bf16_t* gA = A  + (size_t)(bm * BM + srow) * K + scol;
    const bf16_t* gB = BT + (size_t)(bn * BN + srow) * K + scol;
    bf16_t* lA = &As[wave * 512];
    bf16_t* lB = &Bs[wave * 512];

    for (int kt = 0; kt < K / BK; ++kt) {
        const int k0 = kt * BK;
#pragma unroll
        for (int p = 0; p < 4; ++p) {
            gload_lds16(gA + (size_t)(p * 32) * K + k0, lA + p * 2048);
            gload_lds16(gB + (size_t)(p * 32) * K + k0, lB + p * 2048);
        }
        __syncthreads();   // drains vmcnt(0) then barrier
#pragma unroll
        for (int ks = 0; ks < 2; ++ks) {
            bf16x8 af[4], bfr[4];
#pragma unroll
            for (int i = 0; i < 4; ++i)
                af[i] = *(const bf16x8*)&As[(wr * 64 + i * 16 + fr) * BK + ks * 32 + fq * 8];
#pragma unroll
            for (int j = 0; j < 4; ++j)
                bfr[j] = *(const bf16x8*)&Bs[(wc * 64 + j * 16 + fr) * BK + ks * 32 + fq * 8];
#pragma unroll
            for (int i = 0; i < 4; ++i)
#pragma unroll
                for (int j = 0; j < 4; ++j)
                    acc[i][j] = __builtin_amdgcn_mfma_f32_16x16x32_bf16(af[i], bfr[j], acc[i][j], 0, 0, 0);
        }
        __syncthreads();
    }

    // Epilogue. C/D layout: col = lane&15, row = (lane>>4)*4 + reg
    const int orow = bm * BM + wr * 64 + fq * 4;
    const int ocol = bn * BN + wc * 64 + fr;
#pragma unroll
    for (int i = 0; i < 4; ++i) {
#pragma unroll
        for (int j = 0; j < 4; ++j) {
            const int c = ocol + j * 16;
            const float bv = bias[c];
#pragma unroll
            for (int v = 0; v < 4; ++v) {
                const int r = orow + i * 16 + v;
                float xv = acc[i][j][v] + bv;
                if constexpr (GELU_EPI) {
                    float g = 0.5f * xv * (1.0f + erff(xv * 0.70710678118654752f));
                    ((bf16_t*)out)[(size_t)r * N + c] = (bf16_t)g;
                } else {
                    ((float*)out)[(size_t)r * N + c] = xv;
                }
            }
        }
    }
}

// ---------------------------------------------------------------------------
// launch
// ---------------------------------------------------------------------------
extern "C" void kernel_launch(void* const* d_in, const int* in_sizes, int n_in,
                              void* d_out, int out_size, void* d_ws, size_t ws_size,
                              hipStream_t stream) {
    const float* x  = (const float*)d_in[0];   // TOKENS x HIDDEN
    const float* w1 = (const float*)d_in[1];   // HIDDEN x FFN
    const float* b1 = (const float*)d_in[2];   // FFN
    const float* w2 = (const float*)d_in[3];   // FFN x HIDDEN
    const float* b2 = (const float*)d_in[4];   // HIDDEN
    float* y = (float*)d_out;                  // TOKENS x HIDDEN

    // workspace layout (all bf16)
    const size_t xb_elems  = (size_t)TOKENS * HIDDEN;   //  67.1 MB
    const size_t w1t_elems = (size_t)FFN * HIDDEN;      //  33.6 MB
    const size_t w2t_elems = (size_t)HIDDEN * FFN;      //  33.6 MB
    const size_t h_elems   = (size_t)TOKENS * FFN;      // 268.4 MB
    const size_t need = (xb_elems + w1t_elems + w2t_elems + h_elems) * sizeof(bf16_t);
    if (ws_size < need) return;  // fail visibly rather than corrupt memory

    char* ws = (char*)d_ws;
    bf16_t* xb  = (bf16_t*)ws;
    bf16_t* w1t = xb + xb_elems;
    bf16_t* w2t = w1t + w1t_elems;
    bf16_t* h   = w2t + w2t_elems;

    // 1) convert x to bf16
    cvt_f32_to_bf16<<<(TOKENS * HIDDEN / 8 + 255) / 256, 256, 0, stream>>>(
        x, xb, TOKENS * HIDDEN / 8);
    // 2) w1 (HIDDEN x FFN) -> w1t (FFN x HIDDEN) bf16
    transpose_cvt<<<(HIDDEN / 64) * (FFN / 64), 256, 0, stream>>>(w1, w1t, HIDDEN, FFN);
    // 3) w2 (FFN x HIDDEN) -> w2t (HIDDEN x FFN) bf16
    transpose_cvt<<<(FFN / 64) * (HIDDEN / 64), 256, 0, stream>>>(w2, w2t, FFN, HIDDEN);
    // 4) h = gelu(xb @ w1t^T + b1), bf16 out
    gemm_bt<true, TOKENS, FFN, HIDDEN>
        <<<(TOKENS / 128) * (FFN / 128), 256, 0, stream>>>(xb, w1t, b1, h);
    // 5) y = h @ w2t^T + b2, f32 out
    gemm_bt<false, TOKENS, HIDDEN, FFN>
        <<<(TOKENS / 128) * (HIDDEN / 128), 256, 0, stream>>>(h, w2t, b2, y);
}

// Round 4
// 1102.119 us; speedup vs baseline: 1.1907x; 1.1907x over previous
//
#include <hip/hip_runtime.h>
#include <hip/hip_bf16.h>
#include <cstdint>
#include <cstddef>

typedef __bf16 bf16_t;
typedef __bf16 bf16x8 __attribute__((ext_vector_type(8)));
typedef float  f32x4  __attribute__((ext_vector_type(4)));

#define TOKENS 16384
#define HIDDEN 2048
#define FFN    8192

// ---------------------------------------------------------------------------
// async global -> LDS, 16B per lane (wave-uniform LDS base + lane*16)
// ---------------------------------------------------------------------------
__device__ __forceinline__ void gload_lds16(const bf16_t* g, bf16_t* l) {
    __builtin_amdgcn_global_load_lds((const __attribute__((address_space(1))) void*)g,
                                     (__attribute__((address_space(3))) void*)l,
                                     16, 0, 0);
}

// ---------------------------------------------------------------------------
// f32 -> bf16 elementwise convert, 8 elems/thread
// ---------------------------------------------------------------------------
__global__ void cvt_f32_to_bf16(const float* __restrict__ in, bf16_t* __restrict__ out, int n8) {
    int i = blockIdx.x * blockDim.x + threadIdx.x;
    if (i >= n8) return;
    size_t base = (size_t)i * 8;
    f32x4 v0 = *(const f32x4*)&in[base];
    f32x4 v1 = *(const f32x4*)&in[base + 4];
    bf16x8 o;
    o[0] = (bf16_t)v0[0]; o[1] = (bf16_t)v0[1]; o[2] = (bf16_t)v0[2]; o[3] = (bf16_t)v0[3];
    o[4] = (bf16_t)v1[0]; o[5] = (bf16_t)v1[1]; o[6] = (bf16_t)v1[2]; o[7] = (bf16_t)v1[3];
    *(bf16x8*)&out[base] = o;
}

// ---------------------------------------------------------------------------
// Transpose + convert: src (R x C f32) -> dst (C x R bf16)
// ---------------------------------------------------------------------------
__global__ void transpose_cvt(const float* __restrict__ src, bf16_t* __restrict__ dst,
                              int R, int C) {
    __shared__ bf16_t tile[64][66];
    const int tcols = C >> 6;
    const int bx = blockIdx.x % tcols;
    const int by = blockIdx.x / tcols;
    const int c0 = bx << 6, r0 = by << 6;
    const int t = threadIdx.x;
#pragma unroll
    for (int i = 0; i < 16; ++i) {
        int idx = i * 256 + t;
        int rr = idx >> 6, cc = idx & 63;
        tile[rr][cc] = (bf16_t)src[(size_t)(r0 + rr) * C + (c0 + cc)];
    }
    __syncthreads();
#pragma unroll
    for (int i = 0; i < 16; ++i) {
        int idx = i * 256 + t;
        int cc = idx >> 6, rr = idx & 63;
        dst[(size_t)(c0 + cc) * R + (r0 + rr)] = tile[rr][cc];
    }
}

// ---------------------------------------------------------------------------
// 256x256 8-phase GEMM: C(MxN) = A(MxK) @ BT(NxK)^T  [+bias, optional GELU]
// 512 thr = 8 waves (2x4); per-wave 128x64 out; BK=64; 128KB LDS dbuf;
// st_16x32 swizzle; counted vmcnt(6); setprio around MFMA.
//
// LDS element map (bf16): buf0.A=[0,16384) buf1.A=[16384,32768)
//                         buf0.B=[32768,49152) buf1.B=[49152,65536)
// half-tile (+8192 per half) = 128 rows x 64 k; subtile = 512 elems
// (16 rows x 32 k); within-row swizzle byte ^= ((row&8)<<2).
//
// LIVENESS (per wave: A half = wr, read P1+P3 / P5+P7; B half = wc>>1,
// read P1+P2 / P5+P6):
//   buf0.B free after P2, buf0.A free after P3,
//   buf1.B free after P6, buf1.A free after P7.
// STAGE slots: P1:t1.A1 | P3:t2.B0 | P4:t2.B1,t2.A0 | P5:t2.A1
//              | P7:t3.B0 | P8:t3.B1,t3.A0
// vmcnt ledger (2 loads/STAGE): entry P1 = 6 outstanding (t1.B0,B1,A0);
//   P1:+2=8, P3:+2=10, P4:+4=14, VMW(6) retires 8 = all t1 -> P5 safe;
//   P5:+2=8, P7:+2=10, P8:+4=14, VMW(6) retires 8 = all t2 -> next P1 safe.
// ---------------------------------------------------------------------------
#define BAR() __builtin_amdgcn_s_barrier()
#define LGKM0() do { asm volatile("s_waitcnt lgkmcnt(0)" ::: "memory"); \
                     __builtin_amdgcn_sched_barrier(0); } while (0)
#define VMW(n) asm volatile("s_waitcnt vmcnt(" #n ")" ::: "memory")
#define PRIO1() __builtin_amdgcn_s_setprio(1)
#define PRIO0() __builtin_amdgcn_s_setprio(0)

#define DS_A(BUF, QM) do { \
    _Pragma("unroll") for (int mf = 0; mf < 4; ++mf) \
    _Pragma("unroll") for (int ks = 0; ks < 2; ++ks) \
        af[mf][ks] = *(const bf16x8*)&smem[(BUF)*16384 + wr*8192 + (((QM)*4+mf)*2+ks)*512 + lnb_e]; \
} while (0)

#define DS_B(BUF, QN, BB) do { \
    _Pragma("unroll") for (int nf = 0; nf < 2; ++nf) \
    _Pragma("unroll") for (int ks = 0; ks < 2; ++ks) \
        BB[nf][ks] = *(const bf16x8*)&smem[32768 + (BUF)*16384 + bhalf + (((QN)*2+nf)*2+ks)*512 + lnb_e]; \
} while (0)

#define MFMA_Q(QM, QN, BB) do { \
    _Pragma("unroll") for (int ks = 0; ks < 2; ++ks) \
    _Pragma("unroll") for (int mf = 0; mf < 4; ++mf) \
    _Pragma("unroll") for (int nf = 0; nf < 2; ++nf) \
        acc[(QM)*4+mf][(QN)*2+nf] = __builtin_amdgcn_mfma_f32_16x16x32_bf16( \
            af[mf][ks], BB[nf][ks], acc[(QM)*4+mf][(QN)*2+nf], 0, 0, 0); \
} while (0)

// stage one half-tile (128 rows x 64 k = 8192 elems): 2 x global_load_lds/thread
#define STAGE(GBASE, HROWS, TILE, EOFF) do { \
    gload_lds16((GBASE) + aoff0 + (size_t)(HROWS) * K + (TILE) * 64, \
                &smem[(EOFF) + wave * 512]); \
    gload_lds16((GBASE) + aoff1 + (size_t)(HROWS) * K + (TILE) * 64, \
                &smem[(EOFF) + 4096 + wave * 512]); \
} while (0)

template<bool GELU_EPI, int M, int N, int K>
__global__ __launch_bounds__(512, 2)
void gemm8p(const bf16_t* __restrict__ A, const bf16_t* __restrict__ BT,
            const float* __restrict__ bias, void* __restrict__ out)
{
    constexpr int BM = 256, BN = 256;
    constexpr int NT = K / 64, NI = NT / 2;
    constexpr int NBN = N / BN;
    __shared__ __align__(128) bf16_t smem[65536];   // 128 KiB

    const int t = threadIdx.x;
    const int wave = t >> 6, lane = t & 63;
    const int fr = lane & 15, fq = lane >> 4;
    const int wr = wave >> 2, wc = wave & 3;

    int wg = blockIdx.x;
    { const int cpx = (int)gridDim.x >> 3; wg = (wg & 7) * cpx + (wg >> 3); }
    const int bm = wg / NBN, bn = wg % NBN;
    const int rowA0 = bm * BM, colB0 = bn * BN;

    // staging source pre-swizzle: linear LDS byte offset o (within half-tile)
    // -> (row, k):  s=o>>10; ri=(o>>6)&15; b=(o&63)^((ri&8)<<2);
    //               row=(s>>1)*16+ri; k=(s&1)*32+b/2
    int sr0, sk0, sr1, sk1;
    {
        int o = t * 16;
        int ri = (o >> 6) & 15;
        int b = (o & 63) ^ ((ri & 8) << 2);
        sr0 = ((o >> 10) >> 1) * 16 + ri;
        sk0 = ((o >> 10) & 1) * 32 + (b >> 1);
        o = 8192 + t * 16;
        ri = (o >> 6) & 15;
        b = (o & 63) ^ ((ri & 8) << 2);
        sr1 = ((o >> 10) >> 1) * 16 + ri;
        sk1 = ((o >> 10) & 1) * 32 + (b >> 1);
    }
    const bf16_t* gA0 = A + (size_t)rowA0 * K;
    const bf16_t* gB0 = BT + (size_t)colB0 * K;
    const size_t aoff0 = (size_t)sr0 * K + sk0;
    const size_t aoff1 = (size_t)sr1 * K + sk1;

    // read-side swizzled lane base (elements): row fr, k-chunk fq
    const int lnb_e = fr * 32 + ((fq * 8) ^ ((fr & 8) << 1));
    const int bhalf = (wc >> 1) * 8192 + (wc & 1) * 4096;

    f32x4 acc[8][4] = {};
    bf16x8 af[4][2], b0[2][2], b1[2][2];

    // prologue: t0 fully; t1 A0,B0,B1 in flight
    STAGE(gA0, 0,   0, 0);          // t0.A0
    STAGE(gA0, 128, 0, 8192);       // t0.A1
    STAGE(gB0, 0,   0, 32768);      // t0.B0
    STAGE(gB0, 128, 0, 40960);      // t0.B1
    STAGE(gA0, 0,   1, 16384);      // t1.A0
    STAGE(gB0, 0,   1, 49152);      // t1.B0
    STAGE(gB0, 128, 1, 57344);      // t1.B1
    VMW(6);                         // t0 landed; t1 (6 loads) may fly
    BAR();

    for (int i = 0; i < NI - 1; ++i) {
        const int t1 = 2 * i + 1, t2 = 2 * i + 2, t3 = 2 * i + 3;
        // P1: Q00 on buf0
        DS_A(0, 0); DS_B(0, 0, b0);
        STAGE(gA0, 128, t1, 24576);            // buf1.A1 <- t1.A1 (read till prev P7)
        BAR(); LGKM0();
        PRIO1(); MFMA_Q(0, 0, b0); PRIO0();
        BAR();
        // P2: Q01 (no stage; buf0.B still live)
        DS_B(0, 1, b1);
        BAR(); LGKM0();
        PRIO1(); MFMA_Q(0, 1, b1); PRIO0();
        BAR();
        // P3: Q11 (buf0.B free after P2)
        DS_A(0, 1);
        STAGE(gB0, 0, t2, 32768);              // buf0.B0 <- t2.B0
        BAR(); LGKM0();
        PRIO1(); MFMA_Q(1, 1, b1); PRIO0();
        BAR();
        // P4: Q10 regs-only (buf0.A free after P3)
        STAGE(gB0, 128, t2, 40960);            // buf0.B1 <- t2.B1
        STAGE(gA0, 0,   t2, 0);                // buf0.A0 <- t2.A0
        VMW(6);                                // t1 fully landed
        BAR();
        PRIO1(); MFMA_Q(1, 0, b0); PRIO0();
        BAR();
        // P5: Q00 on buf1
        DS_A(1, 0); DS_B(1, 0, b0);
        STAGE(gA0, 128, t2, 8192);             // buf0.A1 <- t2.A1
        BAR(); LGKM0();
        PRIO1(); MFMA_Q(0, 0, b0); PRIO0();
        BAR();
        // P6: Q01
        DS_B(1, 1, b1);
        BAR(); LGKM0();
        PRIO1(); MFMA_Q(0, 1, b1); PRIO0();
        BAR();
        // P7: Q11 (buf1.B free after P6)
        DS_A(1, 1);
        STAGE(gB0, 0, t3, 49152);              // buf1.B0 <- t3.B0
        BAR(); LGKM0();
        PRIO1(); MFMA_Q(1, 1, b1); PRIO0();
        BAR();
        // P8: Q10 (buf1.A free after P7)
        STAGE(gB0, 128, t3, 57344);            // buf1.B1 <- t3.B1
        STAGE(gA0, 0,   t3, 16384);            // buf1.A0 <- t3.A0
        VMW(6);                                // t2 fully landed
        BAR();
        PRIO1(); MFMA_Q(1, 0, b0); PRIO0();
        BAR();
    }

    // peeled last iteration: tile NT-2 in buf0, NT-1 in buf1; no new staging
    DS_A(0, 0); DS_B(0, 0, b0);
    STAGE(gA0, 128, NT - 1, 24576);            // buf1.A1 <- (NT-1).A1
    BAR(); LGKM0();
    PRIO1(); MFMA_Q(0, 0, b0); PRIO0();
    BAR();
    DS_B(0, 1, b1);
    BAR(); LGKM0();
    PRIO1(); MFMA_Q(0, 1, b1); PRIO0();
    BAR();
    DS_A(0, 1);
    BAR(); LGKM0();
    PRIO1(); MFMA_Q(1, 1, b1); PRIO0();
    BAR();
    VMW(0);                                    // drain: buf1 complete
    BAR();
    PRIO1(); MFMA_Q(1, 0, b0); PRIO0();
    BAR();
    DS_A(1, 0); DS_B(1, 0, b0);
    BAR(); LGKM0();
    PRIO1(); MFMA_Q(0, 0, b0); PRIO0();
    BAR();
    DS_B(1, 1, b1);
    BAR(); LGKM0();
    PRIO1(); MFMA_Q(0, 1, b1); PRIO0();
    BAR();
    DS_A(1, 1);
    BAR(); LGKM0();
    PRIO1(); MFMA_Q(1, 1, b1); PRIO0();
    MFMA_Q(1, 0, b0);

    // epilogue: C/D layout col=lane&15, row=(lane>>4)*4+reg
    const int orow = rowA0 + wr * 128 + fq * 4;
    const int ocol = colB0 + wc * 64 + fr;
#pragma unroll
    for (int mf = 0; mf < 8; ++mf) {
#pragma unroll
        for (int nf = 0; nf < 4; ++nf) {
            const int c = ocol + nf * 16;
            const float bv = bias[c];
#pragma unroll
            for (int v = 0; v < 4; ++v) {
                const int r = orow + mf * 16 + v;
                float xv = acc[mf][nf][v] + bv;
                if constexpr (GELU_EPI) {
                    float g = 0.5f * xv * (1.0f + erff(xv * 0.70710678118654752f));
                    ((bf16_t*)out)[(size_t)r * N + c] = (bf16_t)g;
                } else {
                    ((float*)out)[(size_t)r * N + c] = xv;
                }
            }
        }
    }
}

// ---------------------------------------------------------------------------
// launch
// ---------------------------------------------------------------------------
extern "C" void kernel_launch(void* const* d_in, const int* in_sizes, int n_in,
                              void* d_out, int out_size, void* d_ws, size_t ws_size,
                              hipStream_t stream) {
    const float* x  = (const float*)d_in[0];
    const float* w1 = (const float*)d_in[1];
    const float* b1 = (const float*)d_in[2];
    const float* w2 = (const float*)d_in[3];
    const float* b2 = (const float*)d_in[4];
    float* y = (float*)d_out;

    const size_t xb_elems  = (size_t)TOKENS * HIDDEN;
    const size_t w1t_elems = (size_t)FFN * HIDDEN;
    const size_t w2t_elems = (size_t)HIDDEN * FFN;
    const size_t h_elems   = (size_t)TOKENS * FFN;
    const size_t need = (xb_elems + w1t_elems + w2t_elems + h_elems) * sizeof(bf16_t);
    if (ws_size < need) return;

    char* ws = (char*)d_ws;
    bf16_t* xb  = (bf16_t*)ws;
    bf16_t* w1t = xb + xb_elems;
    bf16_t* w2t = w1t + w1t_elems;
    bf16_t* h   = w2t + w2t_elems;

    cvt_f32_to_bf16<<<(TOKENS * HIDDEN / 8 + 255) / 256, 256, 0, stream>>>(
        x, xb, TOKENS * HIDDEN / 8);
    transpose_cvt<<<(HIDDEN / 64) * (FFN / 64), 256, 0, stream>>>(w1, w1t, HIDDEN, FFN);
    transpose_cvt<<<(FFN / 64) * (HIDDEN / 64), 256, 0, stream>>>(w2, w2t, FFN, HIDDEN);

    gemm8p<true, TOKENS, FFN, HIDDEN>
        <<<(TOKENS / 256) * (FFN / 256), 512, 0, stream>>>(xb, w1t, b1, h);
    gemm8p<false, TOKENS, HIDDEN, FFN>
        <<<(TOKENS / 256) * (HIDDEN / 256), 512, 0, stream>>>(h, w2t, b2, y);
}